// Round 1
// baseline (51.343 us; speedup 1.0000x reference)
//
#include <hip/hip_runtime.h>

// arDCA logit: out[n,q] = softmax_q( h[400,q] + sum_{j<400} J[400,q,j,tok(n,j)] )
// X is one-hot [4096,400,21] fp32 -> tokenize, then gather-accumulate from a
// transposed, L2-resident J slice Jq[q][j][a] (705 KB).
//
// N=4096, RES=400, Q=21, L=512.

#define NSEQ 4096
#define RESI 400
#define QA   21
#define JQ_ELEMS (21*400*21)       // 176400
#define P_ELEMS  (25*21*4096)      // 2150400
#define LG_ELEMS (21*4096)         // 86016

// K0: Jq[q][j][a] = J[RES][q][j][a];  J is [512][21][512][21]
__global__ void k0_transpose(const float* __restrict__ J, float* __restrict__ Jq) {
    int idx = blockIdx.x * 256 + threadIdx.x;
    if (idx >= JQ_ELEMS) return;
    int q   = idx / (RESI * QA);
    int rem = idx - q * (RESI * QA);
    int j   = rem / QA;
    int a   = rem - j * QA;
    // flat J index: ((RES*Q + q)*L + j)*Q + a
    Jq[idx] = J[((8400 + q) * 512 + j) * 21 + a];
}

// K1: fused tokenize + partial accumulate.
// grid (64 n-tiles, 25 j-chunks of 16), block 512 = {64 n-lanes} x {8 q-rows}
// Each wave: fixed q-row, 64 consecutive n -> J gathers land in one 84B window.
__global__ __launch_bounds__(512) void k1_partial(const float* __restrict__ X,
                                                  const float* __restrict__ Jq,
                                                  float* __restrict__ P) {
    __shared__ float4 xs4[1344];           // 64 n x 4 j x 21 a floats = 21504 B
    __shared__ unsigned char tok[256];     // 64 n x 4 j
    float* xs = (float*)xs4;

    const int tid = threadIdx.x;
    const int n0  = blockIdx.x << 6;       // 64 n per block
    const int j0  = blockIdx.y << 4;       // 16 j per block
    const int nl  = tid & 63;
    const int qr  = tid >> 6;              // 0..7 -> q in {qr, qr+8, qr+16(<21)}

    float acc0 = 0.f, acc1 = 0.f, acc2 = 0.f;
    const float4* Xf4 = (const float4*)X;

    for (int sc = 0; sc < 4; ++sc) {
        const int jb = j0 + (sc << 2);     // multiple of 4 -> 16B-aligned rows
        // stage 64 x (4j*21a) floats = 1344 float4, coalesced, 64B-aligned
        #pragma unroll
        for (int k = 0; k < 3; ++k) {
            int i = tid + (k << 9);
            if (i < 1344) {
                int snl = i / 21;
                int e   = i - snl * 21;
                xs4[i] = Xf4[(n0 + snl) * 2100 + ((jb * 21) >> 2) + e];
            }
        }
        __syncthreads();
        // tokenize: one thread per (n,j) cell scans its 21 floats
        if (tid < 256) {
            int snl = tid & 63, jl = tid >> 6;
            const float* row = xs + snl * 84 + jl * 21;
            int t = 0;
            #pragma unroll
            for (int a = 0; a < 21; ++a)
                if (row[a] > 0.5f) t = a;
            tok[(jl << 6) + snl] = (unsigned char)t;
        }
        __syncthreads();
        // accumulate: wave-uniform (q,j); lanes differ only in token t
        #pragma unroll
        for (int jl = 0; jl < 4; ++jl) {
            int t = tok[(jl << 6) + nl];
            int j = jb + jl;
            acc0 += Jq[(qr * 400 + j) * 21 + t];
            acc1 += Jq[((qr + 8) * 400 + j) * 21 + t];
            if (qr < 5) acc2 += Jq[((qr + 16) * 400 + j) * 21 + t];
        }
        __syncthreads();   // protect xs/tok before next stage
    }

    // P laid out [chunk][q][n] -> coalesced writes and coalesced K2 reads
    const int c = blockIdx.y;
    P[((c * 21 + qr) << 12) + n0 + nl] = acc0;
    P[((c * 21 + qr + 8) << 12) + n0 + nl] = acc1;
    if (qr < 5) P[((c * 21 + qr + 16) << 12) + n0 + nl] = acc2;
}

// K2: logits[q][n] = h[400,q] + sum_c P[c][q][n]   (fully coalesced)
__global__ void k2_reduce(const float* __restrict__ P, const float* __restrict__ h,
                          float* __restrict__ logits) {
    int idx = blockIdx.x * 256 + threadIdx.x;   // exactly 86016 = 336*256
    int q = idx >> 12;
    int n = idx & 4095;
    float s = h[8400 + q];
    #pragma unroll
    for (int c = 0; c < 25; ++c)
        s += P[((c * 21 + q) << 12) + n];
    logits[idx] = s;
}

// K3: per-n softmax over 21 classes; reads [q][n] coalesced, writes [n][q]
__global__ void k3_softmax(const float* __restrict__ logits, float* __restrict__ out) {
    int n = blockIdx.x * 256 + threadIdx.x;     // exactly 4096 = 16*256
    float v[QA];
    float m = -1e30f;
    #pragma unroll
    for (int q = 0; q < QA; ++q) {
        v[q] = logits[(q << 12) + n];
        m = fmaxf(m, v[q]);
    }
    float s = 0.f;
    #pragma unroll
    for (int q = 0; q < QA; ++q) {
        v[q] = __expf(v[q] - m);
        s += v[q];
    }
    float inv = 1.0f / s;
    #pragma unroll
    for (int q = 0; q < QA; ++q)
        out[n * QA + q] = v[q] * inv;
}

extern "C" void kernel_launch(void* const* d_in, const int* in_sizes, int n_in,
                              void* d_out, int out_size, void* d_ws, size_t ws_size,
                              hipStream_t stream) {
    const float* X = (const float*)d_in[0];   // [4096,400,21] one-hot fp32
    const float* h = (const float*)d_in[1];   // [512,21]
    const float* J = (const float*)d_in[2];   // [512,21,512,21]
    float* out = (float*)d_out;               // [4096,21] fp32

    float* Jq     = (float*)d_ws;             // 176400 floats
    float* P      = Jq + JQ_ELEMS;            // 2150400 floats
    float* logits = P + P_ELEMS;              // 86016 floats
    // total ws use: 9,651,264 bytes

    k0_transpose<<<690, 256, 0, stream>>>(J, Jq);
    k1_partial<<<dim3(64, 25), 512, 0, stream>>>(X, Jq, P);
    k2_reduce<<<336, 256, 0, stream>>>(P, h, logits);
    k3_softmax<<<16, 256, 0, stream>>>(logits, out);
}